// Round 1
// baseline (1581.592 us; speedup 1.0000x reference)
//
#include <hip/hip_runtime.h>
#include <hip/hip_bf16.h>
#include <math.h>

#define NROWS 131072
#define E 1024
#define L 512
#define DD 256
#define NI 50
#define CAP 2048

typedef __attribute__((ext_vector_type(8))) short bf16x8;
typedef __attribute__((ext_vector_type(4))) float f32x4;

__device__ __forceinline__ unsigned short f2bf(float f) {
  unsigned u = __float_as_uint(f);
  unsigned r = (u + 0x7FFFu + ((u >> 16) & 1u)) >> 16;   // RNE
  return (unsigned short)r;
}
__device__ __forceinline__ float bf2f(unsigned short b) {
  return __uint_as_float(((unsigned)b) << 16);
}
__device__ __forceinline__ float frcp(float x) { return __builtin_amdgcn_rcpf(x); }
__device__ __forceinline__ float fsig(float x) { return frcp(1.0f + __expf(-x)); }
__device__ __forceinline__ float ftanh(float x) { return 2.0f * frcp(1.0f + __expf(-2.0f * x)) - 1.0f; }

#define GLDS16(gp, lp)                                                        \
  __builtin_amdgcn_global_load_lds(                                           \
      (const __attribute__((address_space(1))) void*)(gp),                    \
      (__attribute__((address_space(3))) void*)(lp), 16, 0, 0)

// ---------------------------------------------------------------- K0: init
__global__ void k0_init(const float* __restrict__ Wc, const float* __restrict__ Wv,
                        const float* __restrict__ Wu,
                        unsigned short* __restrict__ WcB, unsigned short* __restrict__ W2B,
                        float* __restrict__ Aws, unsigned* __restrict__ hist,
                        unsigned* __restrict__ scalU) {
  const int i0 = blockIdx.x * blockDim.x + threadIdx.x;
  const int str = gridDim.x * blockDim.x;
  if (i0 < 16) scalU[i0] = 0u;
  for (int k = i0; k < 65536; k += str) hist[k] = 0u;
  for (int k = i0; k < NROWS * 2; k += str) Aws[k] = 0.f;
  for (int k = i0; k < L * E; k += str) WcB[k] = f2bf(Wc[k]);
  for (int k = i0; k < DD * L; k += str) { W2B[k] = f2bf(Wv[k]); W2B[DD * L + k] = f2bf(Wu[k]); }
}

// --------------------------------------------- K1: h = relu(x @ Wc^T + bc)
// 128x128 tile, BK=64, 4 waves (2x2 of 64x64), XOR-swizzled LDS.
__global__ __launch_bounds__(256) void k1_gemm1(const float* __restrict__ x,
                                                const unsigned short* __restrict__ WcB,
                                                const float* __restrict__ bc,
                                                unsigned short* __restrict__ hB) {
  __shared__ __align__(16) unsigned short xs[128 * 64];
  __shared__ __align__(16) unsigned short wt[128 * 64];
  const int tid = threadIdx.x;
  const int lane = tid & 63;
  const int wv = tid >> 6;
  const int cbk = blockIdx.x & 3;
  const int rbk = blockIdx.x >> 2;
  const int row0 = rbk << 7;
  const int col0 = cbk << 7;
  const int wr = wv >> 1, wc = wv & 1;
  const int q = lane >> 4, c15 = lane & 15;

  f32x4 acc[4][4];
#pragma unroll
  for (int i = 0; i < 4; ++i)
#pragma unroll
    for (int j = 0; j < 4; ++j) acc[i][j] = {0.f, 0.f, 0.f, 0.f};

  for (int kk = 0; kk < E; kk += 64) {
    __syncthreads();
    // B tile (weights, bf16) via async global->LDS, source-swizzled
#pragma unroll
    for (int i = 0; i < 4; ++i) {
      const int g = (wv << 2) + i;
      const int slot = (g << 6) + lane;
      const int j = slot >> 3;
      const int s = slot & 7;
      const int k8 = s ^ (j & 7);
      GLDS16(WcB + (size_t)(col0 + j) * E + kk + (k8 << 3), wt + (g << 9));
    }
    // A tile (x fp32 -> bf16) via VGPR convert + swizzled ds_write
#pragma unroll
    for (int i = 0; i < 4; ++i) {
      const int ci = (i << 8) + tid;   // 0..1023 chunks of 16B
      const int r = ci >> 3;
      const int s = ci & 7;
      const float* gp = x + (size_t)(row0 + r) * E + kk + (s << 3);
      const float4 v0 = *(const float4*)gp;
      const float4 v1 = *(const float4*)(gp + 4);
      bf16x8 hv;
      hv[0] = (short)f2bf(v0.x); hv[1] = (short)f2bf(v0.y);
      hv[2] = (short)f2bf(v0.z); hv[3] = (short)f2bf(v0.w);
      hv[4] = (short)f2bf(v1.x); hv[5] = (short)f2bf(v1.y);
      hv[6] = (short)f2bf(v1.z); hv[7] = (short)f2bf(v1.w);
      *(bf16x8*)(xs + (r << 6) + ((s ^ (r & 7)) << 3)) = hv;
    }
    __syncthreads();
#pragma unroll
    for (int ks = 0; ks < 2; ++ks) {
      const int k8 = (ks << 2) + q;
      bf16x8 af[4], bfr[4];
#pragma unroll
      for (int mt = 0; mt < 4; ++mt) {
        const int rr = (wr << 6) + (mt << 4) + c15;
        af[mt] = *(const bf16x8*)(xs + (rr << 6) + ((k8 ^ (rr & 7)) << 3));
      }
#pragma unroll
      for (int nt = 0; nt < 4; ++nt) {
        const int jj = (wc << 6) + (nt << 4) + c15;
        bfr[nt] = *(const bf16x8*)(wt + (jj << 6) + ((k8 ^ (jj & 7)) << 3));
      }
#pragma unroll
      for (int mt = 0; mt < 4; ++mt)
#pragma unroll
        for (int nt = 0; nt < 4; ++nt)
          acc[mt][nt] = __builtin_amdgcn_mfma_f32_16x16x32_bf16(af[mt], bfr[nt], acc[mt][nt], 0, 0, 0);
    }
  }
  // epilogue: relu + bf16 pack-pairs (shfl) + dword stores by even lanes
#pragma unroll
  for (int nt = 0; nt < 4; ++nt) {
    const int colg = col0 + (wc << 6) + (nt << 4) + c15;
    const float bias = bc[colg];
#pragma unroll
    for (int mt = 0; mt < 4; ++mt) {
#pragma unroll
      for (int r = 0; r < 4; ++r) {
        const int rowg = row0 + (wr << 6) + (mt << 4) + (q << 2) + r;
        float v = acc[mt][nt][r] + bias;
        v = v > 0.f ? v : 0.f;
        const unsigned short hb = f2bf(v);
        const unsigned short ob = (unsigned short)__shfl_xor((int)hb, 1, 64);
        if (!(lane & 1)) {
          *(unsigned*)(hB + (size_t)rowg * L + colg) = (unsigned)hb | ((unsigned)ob << 16);
        }
      }
    }
  }
}

// ------------- K2: a||b GEMM + tanh/sigmoid + (a*b)@Wa^T partial -> atomic A
// tile 128 rows x 128 cols (cols = 64 a-cols then same 64 b-cols), 4 waves of
// 32 rows x 128 cols (mt=2, nt=8) so a (nt) and b (nt+4) pair in-register.
__global__ __launch_bounds__(256) void k2_gemm2(const unsigned short* __restrict__ hB,
                                                const unsigned short* __restrict__ W2B,
                                                const float* __restrict__ bv,
                                                const float* __restrict__ bu,
                                                const float* __restrict__ Wa,
                                                float* __restrict__ Aws) {
  __shared__ __align__(16) unsigned short hs[128 * 64];
  __shared__ __align__(16) unsigned short wt[128 * 64];
  const int tid = threadIdx.x, lane = tid & 63, wv = tid >> 6;
  const int cbk = blockIdx.x & 3, rbk = blockIdx.x >> 2;
  const int row0 = rbk << 7;
  const int q = lane >> 4, c15 = lane & 15;

  f32x4 acc[2][8];
#pragma unroll
  for (int i = 0; i < 2; ++i)
#pragma unroll
    for (int j = 0; j < 8; ++j) acc[i][j] = {0.f, 0.f, 0.f, 0.f};

  for (int kk = 0; kk < L; kk += 64) {
    __syncthreads();
#pragma unroll
    for (int i = 0; i < 4; ++i) {
      const int g = (wv << 2) + i;
      const int slot = (g << 6) + lane;
      const int j = slot >> 3;
      const int s = slot & 7;
      const int k8 = s ^ (j & 7);
      GLDS16(hB + (size_t)(row0 + j) * L + kk + (k8 << 3), hs + (g << 9));
      const int w2row = (j < 64) ? ((cbk << 6) + j) : (256 + (cbk << 6) + (j - 64));
      GLDS16(W2B + (size_t)w2row * L + kk + (k8 << 3), wt + (g << 9));
    }
    __syncthreads();
#pragma unroll
    for (int ks = 0; ks < 2; ++ks) {
      const int k8 = (ks << 2) + q;
      bf16x8 af[2], bfr[8];
#pragma unroll
      for (int mt = 0; mt < 2; ++mt) {
        const int rr = (wv << 5) + (mt << 4) + c15;
        af[mt] = *(const bf16x8*)(hs + (rr << 6) + ((k8 ^ (rr & 7)) << 3));
      }
#pragma unroll
      for (int nt = 0; nt < 8; ++nt) {
        const int jj = (nt << 4) + c15;
        bfr[nt] = *(const bf16x8*)(wt + (jj << 6) + ((k8 ^ (jj & 7)) << 3));
      }
#pragma unroll
      for (int mt = 0; mt < 2; ++mt)
#pragma unroll
        for (int nt = 0; nt < 8; ++nt)
          acc[mt][nt] = __builtin_amdgcn_mfma_f32_16x16x32_bf16(af[mt], bfr[nt], acc[mt][nt], 0, 0, 0);
    }
  }
  // epilogue: ab = tanh(.)*sigmoid(.), partial A = ab . Wa over this block's 64 d-cols
  float wa0v[4], wa1v[4], bvv[4], buv[4];
#pragma unroll
  for (int nt = 0; nt < 4; ++nt) {
    const int d = (cbk << 6) + (nt << 4) + c15;
    wa0v[nt] = Wa[d]; wa1v[nt] = Wa[DD + d];
    bvv[nt] = bv[d];  buv[nt] = bu[d];
  }
#pragma unroll
  for (int mt = 0; mt < 2; ++mt) {
#pragma unroll
    for (int r = 0; r < 4; ++r) {
      const int rowg = row0 + (wv << 5) + (mt << 4) + (q << 2) + r;
      float p0 = 0.f, p1 = 0.f;
#pragma unroll
      for (int nt = 0; nt < 4; ++nt) {
        const float av = ftanh(acc[mt][nt][r] + bvv[nt]);
        const float bx = fsig(acc[mt][nt + 4][r] + buv[nt]);
        const float ab = av * bx;
        p0 += ab * wa0v[nt];
        p1 += ab * wa1v[nt];
      }
#pragma unroll
      for (int off = 1; off < 16; off <<= 1) {
        p0 += __shfl_xor(p0, off, 64);
        p1 += __shfl_xor(p1, off, 64);
      }
      if (c15 == 0) {
        atomicAdd(&Aws[(rowg << 1)], p0);
        atomicAdd(&Aws[(rowg << 1) + 1], p1);
      }
    }
  }
}

// ------ K3: raw_attention out, softmax Z, bag partials S=sum(exp(A)*h.Wbag), hist
__global__ void k3_attn(const unsigned short* __restrict__ hB,
                        const float* __restrict__ Aws,
                        const float* __restrict__ ba,
                        const float* __restrict__ Wbag,
                        const int* __restrict__ lblp,
                        float* __restrict__ out,
                        unsigned* __restrict__ hist,
                        float* __restrict__ scalF) {
  const int tid = blockIdx.x * blockDim.x + threadIdx.x;
  const int lane = tid & 63;
  const int wid = tid >> 6;
  const int nW = (gridDim.x * blockDim.x) >> 6;
  const int lbl = *lblp;
  float wb0[8], wb1[8];
#pragma unroll
  for (int i = 0; i < 8; ++i) { wb0[i] = Wbag[(lane << 3) + i]; wb1[i] = Wbag[L + (lane << 3) + i]; }
  const float ba0 = ba[0], ba1 = ba[1];
  float z0 = 0.f, z1 = 0.f, s0 = 0.f, s1 = 0.f;
  for (int row = wid; row < NROWS; row += nW) {
    const uint4 hv = *(const uint4*)(hB + (size_t)row * L + (lane << 3));
    float t0 = 0.f, t1 = 0.f;
    const unsigned uu[4] = {hv.x, hv.y, hv.z, hv.w};
#pragma unroll
    for (int i = 0; i < 4; ++i) {
      const float flo = __uint_as_float(uu[i] << 16);
      const float fhi = __uint_as_float(uu[i] & 0xFFFF0000u);
      t0 += flo * wb0[2 * i] + fhi * wb0[2 * i + 1];
      t1 += flo * wb1[2 * i] + fhi * wb1[2 * i + 1];
    }
#pragma unroll
    for (int off = 32; off; off >>= 1) { t0 += __shfl_xor(t0, off, 64); t1 += __shfl_xor(t1, off, 64); }
    if (lane == 0) {
      const float A0 = Aws[row << 1] + ba0;
      const float A1 = Aws[(row << 1) + 1] + ba1;
      out[4 + row] = A0;
      out[4 + NROWS + row] = A1;
      const float w0 = __expf(A0), w1 = __expf(A1);
      z0 += w0; z1 += w1; s0 += w0 * t0; s1 += w1 * t1;
      unsigned u = __float_as_uint(lbl == 0 ? A0 : A1);
      u = (u & 0x80000000u) ? ~u : (u | 0x80000000u);
      atomicAdd(&hist[u >> 16], 1u);
    }
  }
  if (lane == 0) {
    atomicAdd(&scalF[0], z0); atomicAdd(&scalF[1], z1);
    atomicAdd(&scalF[2], s0); atomicAdd(&scalF[3], s1);
  }
}

// -------- K4: hist scan -> threshold bins; bag logits + y_proba -> out[0..3]
__global__ void k4_scan(const unsigned* __restrict__ hist,
                        const float* __restrict__ scalF,
                        unsigned* __restrict__ scalU,
                        const float* __restrict__ bbag,
                        float* __restrict__ out) {
  __shared__ unsigned csum[256];
  const int t = threadIdx.x;
  unsigned s = 0;
  for (int b = 0; b < 256; ++b) s += hist[t * 256 + b];
  csum[t] = s;
  __syncthreads();
  if (t == 0) {
    unsigned acc = 0; int ch = 255;
    for (; ch > 0; --ch) { if (acc + csum[ch] >= NI) break; acc += csum[ch]; }
    unsigned binHi = 0;
    for (int b = ch * 256 + 255; b >= ch * 256; --b) { acc += hist[b]; if (acc >= NI) { binHi = (unsigned)b; break; } }
    scalU[6] = binHi;
    acc = 0; int cl = 0;
    for (; cl < 255; ++cl) { if (acc + csum[cl] >= NI) break; acc += csum[cl]; }
    unsigned binLo = 65535;
    for (int b = cl * 256; b < cl * 256 + 256; ++b) { acc += hist[b]; if (acc >= NI) { binLo = (unsigned)b; break; } }
    scalU[7] = binLo;
    const float l0 = scalF[2] / scalF[0] + bbag[0];
    const float l1 = scalF[3] / scalF[1] + bbag[1];
    const float m = fmaxf(l0, l1);
    const float e0 = __expf(l0 - m), e1 = __expf(l1 - m);
    const float inv = 1.0f / (e0 + e1);
    out[0] = l0; out[1] = l1; out[2] = e0 * inv; out[3] = e1 * inv;
  }
}

// ----------------------------- K5: collect top/bottom candidates by bin
__global__ void k5_collect(const float* __restrict__ out,
                           const int* __restrict__ lblp,
                           unsigned* __restrict__ scalU,
                           unsigned* __restrict__ chK, unsigned* __restrict__ chI,
                           unsigned* __restrict__ clK, unsigned* __restrict__ clI) {
  const unsigned binHi = scalU[6], binLo = scalU[7];
  const int lbl = *lblp;
  const float* Ap = out + 4 + (size_t)lbl * NROWS;
  for (int n = blockIdx.x * blockDim.x + threadIdx.x; n < NROWS; n += gridDim.x * blockDim.x) {
    unsigned u = __float_as_uint(Ap[n]);
    u = (u & 0x80000000u) ? ~u : (u | 0x80000000u);
    const unsigned bin = u >> 16;
    if (bin >= binHi) { unsigned p = atomicAdd(&scalU[4], 1u); if (p < CAP) { chK[p] = u; chI[p] = (unsigned)n; } }
    if (bin <= binLo) { unsigned p = atomicAdd(&scalU[5], 1u); if (p < CAP) { clK[p] = u; clI[p] = (unsigned)n; } }
  }
}

// -------- K6: exact rank selection + instance logits + SmoothTop1SVM loss
__global__ __launch_bounds__(256) void k6_loss(const unsigned* __restrict__ scalU,
                                               const unsigned* __restrict__ chK, const unsigned* __restrict__ chI,
                                               const unsigned* __restrict__ clK, const unsigned* __restrict__ clI,
                                               const unsigned short* __restrict__ hB,
                                               const float* __restrict__ Winst,
                                               const float* __restrict__ binst,
                                               const int* __restrict__ lblp,
                                               float* __restrict__ out) {
  __shared__ unsigned kH[CAP], iH[CAP], kL[CAP], iL[CAP];
  __shared__ int selT[NI], selB[NI];
  __shared__ float lossA[256];
  const int t = threadIdx.x;
  const int lbl = *lblp;
  const unsigned cH = scalU[4], cL = scalU[5];
  const int nH = (int)(cH < CAP ? cH : CAP);
  const int nL = (int)(cL < CAP ? cL : CAP);
  if (t < NI) { selT[t] = 0; selB[t] = 0; }
  for (int i = t; i < nH; i += 256) { kH[i] = chK[i]; iH[i] = chI[i]; }
  for (int i = t; i < nL; i += 256) { kL[i] = clK[i]; iL[i] = clI[i]; }
  __syncthreads();
  for (int c = t; c < nH; c += 256) {
    const unsigned k = kH[c], id = iH[c];
    int rank = 0;
    for (int j = 0; j < nH; ++j) rank += (kH[j] > k) || (kH[j] == k && iH[j] < id);
    if (rank < NI) selT[rank] = (int)id;
  }
  for (int c = t; c < nL; c += 256) {
    const unsigned k = kL[c], id = iL[c];
    int rank = 0;
    for (int j = 0; j < nL; ++j) rank += (kL[j] < k) || (kL[j] == k && iL[j] < id);
    if (rank < NI) selB[rank] = (int)id;
  }
  __syncthreads();
  float loss = 0.f;
  if (t < 2 * NI) {
    const int idx = (t < NI) ? selT[t] : selB[t - NI];
    const int target = (t < NI) ? 1 : 0;
    const unsigned short* hp = hB + (size_t)idx * L;
    const float* w0 = Winst + (size_t)lbl * 2 * L;
    const float* w1 = w0 + L;
    float l0 = binst[lbl * 2 + 0], l1 = binst[lbl * 2 + 1];
    for (int k = 0; k < L; ++k) {
      const float hv = bf2f(hp[k]);
      l0 += hv * w0[k];
      l1 += hv * w1[k];
    }
    const float z0 = l0 + (target ? 1.0f : 0.0f);
    const float z1 = l1 + (target ? 0.0f : 1.0f);
    const float m = fmaxf(z0, z1);
    const float lse = m + logf(__expf(z0 - m) + __expf(z1 - m));
    loss = lse - (target ? l1 : l0);
  }
  lossA[t] = loss;
  __syncthreads();
  for (int sft = 128; sft; sft >>= 1) {
    if (t < sft) lossA[t] += lossA[t + sft];
    __syncthreads();
  }
  if (t == 0) out[4 + 2 * NROWS] = lossA[0] / 100.0f;
}

extern "C" void kernel_launch(void* const* d_in, const int* in_sizes, int n_in,
                              void* d_out, int out_size, void* d_ws, size_t ws_size,
                              hipStream_t stream) {
  const float* x     = (const float*)d_in[0];
  const int*   lbl   = (const int*)d_in[1];
  const float* Wc    = (const float*)d_in[2];
  const float* bc    = (const float*)d_in[3];
  const float* Wv    = (const float*)d_in[4];
  const float* bv    = (const float*)d_in[5];
  const float* Wu    = (const float*)d_in[6];
  const float* bu    = (const float*)d_in[7];
  const float* Wa    = (const float*)d_in[8];
  const float* ba    = (const float*)d_in[9];
  const float* Winst = (const float*)d_in[10];
  const float* binst = (const float*)d_in[11];
  const float* Wbag  = (const float*)d_in[12];
  const float* bbag  = (const float*)d_in[13];
  float* out = (float*)d_out;
  char* ws = (char*)d_ws;

  unsigned short* hB   = (unsigned short*)(ws);                  // 134217728 B
  unsigned short* WcB  = (unsigned short*)(ws + 134217728LL);    // 1048576 B
  unsigned short* W2B  = (unsigned short*)(ws + 135266304LL);    // 524288 B
  float*          Aws  = (float*)(ws + 135790592LL);             // 1048576 B
  unsigned*       hist = (unsigned*)(ws + 136839168LL);          // 262144 B
  float*          scalF= (float*)(ws + 137101312LL);             // 64 B (+pad)
  unsigned*       scalU= (unsigned*)(ws + 137101312LL);
  unsigned*       chK  = (unsigned*)(ws + 137101568LL);
  unsigned*       chI  = chK + CAP;
  unsigned*       clK  = chI + CAP;
  unsigned*       clI  = clK + CAP;

  k0_init<<<2048, 256, 0, stream>>>(Wc, Wv, Wu, WcB, W2B, Aws, hist, scalU);
  k1_gemm1<<<4096, 256, 0, stream>>>(x, WcB, bc, hB);
  k2_gemm2<<<4096, 256, 0, stream>>>(hB, W2B, bv, bu, Wa, Aws);
  k3_attn<<<2048, 256, 0, stream>>>(hB, Aws, ba, Wbag, lbl, out, hist, scalF);
  k4_scan<<<1, 256, 0, stream>>>(hist, scalF, scalU, bbag, out);
  k5_collect<<<512, 256, 0, stream>>>(out, lbl, scalU, chK, chI, clK, clI);
  k6_loss<<<1, 256, 0, stream>>>(scalU, chK, chI, clK, clI, hB, Winst, binst, lbl, out);
}

// Round 2
// 1319.008 us; speedup vs baseline: 1.1991x; 1.1991x over previous
//
#include <hip/hip_runtime.h>
#include <hip/hip_bf16.h>
#include <math.h>

#define NROWS 131072
#define E 1024
#define L 512
#define DD 256
#define NI 50
#define CAP 2048
#define NBINS 16384

typedef __attribute__((ext_vector_type(8))) short bf16x8;
typedef __attribute__((ext_vector_type(4))) float f32x4;

__device__ __forceinline__ unsigned short f2bf(float f) {
  unsigned u = __float_as_uint(f);
  unsigned r = (u + 0x7FFFu + ((u >> 16) & 1u)) >> 16;   // RNE
  return (unsigned short)r;
}
__device__ __forceinline__ float bf2f(unsigned short b) {
  return __uint_as_float(((unsigned)b) << 16);
}
__device__ __forceinline__ float frcp(float x) { return __builtin_amdgcn_rcpf(x); }
__device__ __forceinline__ float fsig(float x) { return frcp(1.0f + __expf(-x)); }
__device__ __forceinline__ float ftanh(float x) { return 2.0f * frcp(1.0f + __expf(-2.0f * x)) - 1.0f; }
__device__ __forceinline__ unsigned encf(float f) {
  unsigned u = __float_as_uint(f);
  return (u & 0x80000000u) ? ~u : (u | 0x80000000u);
}
__device__ __forceinline__ float decf(unsigned e) {
  unsigned b = (e & 0x80000000u) ? (e & 0x7FFFFFFFu) : ~e;
  return __uint_as_float(b);
}

#define GLDS16(gp, lp)                                                        \
  __builtin_amdgcn_global_load_lds(                                           \
      (const __attribute__((address_space(1))) void*)(gp),                    \
      (__attribute__((address_space(3))) void*)(lp), 16, 0, 0)

// ---------------------------------------------------------------- K0: init
__global__ void k0_init(const float* __restrict__ Wc, const float* __restrict__ Wv,
                        const float* __restrict__ Wu,
                        unsigned short* __restrict__ WcB, unsigned short* __restrict__ W2B,
                        float* __restrict__ Aws, float* __restrict__ tws,
                        unsigned* __restrict__ hist,
                        float* __restrict__ scalF, unsigned* __restrict__ scalU) {
  const int i0 = blockIdx.x * blockDim.x + threadIdx.x;
  const int str = gridDim.x * blockDim.x;
  if (i0 < 4) scalF[i0] = 0.f;
  if (i0 < 16) scalU[i0] = (i0 == 0) ? 0xFFFFFFFFu : 0u;
  for (int k = i0; k < NBINS; k += str) hist[k] = 0u;
  for (int k = i0; k < NROWS * 2; k += str) { Aws[k] = 0.f; tws[k] = 0.f; }
  for (int k = i0; k < L * E; k += str) WcB[k] = f2bf(Wc[k]);
  for (int k = i0; k < DD * L; k += str) { W2B[k] = f2bf(Wv[k]); W2B[DD * L + k] = f2bf(Wu[k]); }
}

// ------------- K1: h = relu(x @ Wc^T + bc); also t = h @ Wbag^T (partial, atomic)
// 128 rows x 256 cols, BK=64, 4 waves (2x2 of 64x128), XOR-swizzled LDS.
__global__ __launch_bounds__(256) void k1_gemm1(const float* __restrict__ x,
                                                const unsigned short* __restrict__ WcB,
                                                const float* __restrict__ bc,
                                                const float* __restrict__ Wbag,
                                                unsigned short* __restrict__ hB,
                                                float* __restrict__ tws) {
  __shared__ __align__(16) unsigned short xs[128 * 64];   // 16KB
  __shared__ __align__(16) unsigned short wt[256 * 64];   // 32KB
  const int tid = threadIdx.x;
  const int lane = tid & 63;
  const int wv = tid >> 6;
  const int cbk = blockIdx.x & 1;
  const int rbk = blockIdx.x >> 1;
  const int row0 = rbk << 7;
  const int col0 = cbk << 8;
  const int wr = wv >> 1, wc = wv & 1;
  const int q = lane >> 4, c15 = lane & 15;

  f32x4 acc[4][8];
#pragma unroll
  for (int i = 0; i < 4; ++i)
#pragma unroll
    for (int j = 0; j < 8; ++j) acc[i][j] = {0.f, 0.f, 0.f, 0.f};

  for (int kk = 0; kk < E; kk += 64) {
    __syncthreads();
    // weight tile: 256 cols x 64 k, bf16, async global->LDS, source-swizzled
#pragma unroll
    for (int i = 0; i < 8; ++i) {
      const int g = (wv << 3) + i;
      const int slot = (g << 6) + lane;
      const int j = slot >> 3;
      const int s = slot & 7;
      const int k8 = s ^ (j & 7);
      GLDS16(WcB + (size_t)(col0 + j) * E + kk + (k8 << 3), wt + (g << 9));
    }
    // x tile (fp32 -> bf16) via VGPR convert + swizzled ds_write
#pragma unroll
    for (int i = 0; i < 4; ++i) {
      const int ci = (i << 8) + tid;   // 0..1023 chunks of 8 elems
      const int r = ci >> 3;
      const int s = ci & 7;
      const float* gp = x + (size_t)(row0 + r) * E + kk + (s << 3);
      const float4 v0 = *(const float4*)gp;
      const float4 v1 = *(const float4*)(gp + 4);
      bf16x8 hv;
      hv[0] = (short)f2bf(v0.x); hv[1] = (short)f2bf(v0.y);
      hv[2] = (short)f2bf(v0.z); hv[3] = (short)f2bf(v0.w);
      hv[4] = (short)f2bf(v1.x); hv[5] = (short)f2bf(v1.y);
      hv[6] = (short)f2bf(v1.z); hv[7] = (short)f2bf(v1.w);
      *(bf16x8*)(xs + (r << 6) + ((s ^ (r & 7)) << 3)) = hv;
    }
    __syncthreads();
#pragma unroll
    for (int ks = 0; ks < 2; ++ks) {
      const int ch = (ks << 2) + q;
      bf16x8 af[4];
#pragma unroll
      for (int mt = 0; mt < 4; ++mt) {
        const int rr = (wr << 6) + (mt << 4) + c15;
        af[mt] = *(const bf16x8*)(xs + (rr << 6) + ((ch ^ (rr & 7)) << 3));
      }
#pragma unroll
      for (int nt = 0; nt < 8; ++nt) {
        const int jj = (wc << 7) + (nt << 4) + c15;
        const bf16x8 bb = *(const bf16x8*)(wt + (jj << 6) + ((ch ^ (jj & 7)) << 3));
#pragma unroll
        for (int mt = 0; mt < 4; ++mt)
          acc[mt][nt] = __builtin_amdgcn_mfma_f32_16x16x32_bf16(af[mt], bb, acc[mt][nt], 0, 0, 0);
      }
    }
  }
  // epilogue: bias+relu, bag-dot partial, bf16 pack-pairs + dword stores
  float bias[8], wb0[8], wb1[8];
#pragma unroll
  for (int nt = 0; nt < 8; ++nt) {
    const int colg = col0 + (wc << 7) + (nt << 4) + c15;
    bias[nt] = bc[colg];
    wb0[nt] = Wbag[colg];
    wb1[nt] = Wbag[L + colg];
  }
#pragma unroll
  for (int mt = 0; mt < 4; ++mt) {
#pragma unroll
    for (int r = 0; r < 4; ++r) {
      const int rowg = row0 + (wr << 6) + (mt << 4) + (q << 2) + r;
      float tp0 = 0.f, tp1 = 0.f;
#pragma unroll
      for (int nt = 0; nt < 8; ++nt) {
        const int colg = col0 + (wc << 7) + (nt << 4) + c15;
        float v = acc[mt][nt][r] + bias[nt];
        v = v > 0.f ? v : 0.f;
        tp0 += v * wb0[nt];
        tp1 += v * wb1[nt];
        const unsigned short hb = f2bf(v);
        const unsigned short ob = (unsigned short)__shfl_xor((int)hb, 1, 64);
        if (!(lane & 1)) {
          *(unsigned*)(hB + (size_t)rowg * L + colg) = (unsigned)hb | ((unsigned)ob << 16);
        }
      }
#pragma unroll
      for (int off = 1; off < 16; off <<= 1) {
        tp0 += __shfl_xor(tp0, off, 64);
        tp1 += __shfl_xor(tp1, off, 64);
      }
      if (c15 == 0) {
        atomicAdd(&tws[(rowg << 1)], tp0);
        atomicAdd(&tws[(rowg << 1) + 1], tp1);
      }
    }
  }
}

// ------------- K2: a||b GEMM + tanh/sigmoid + (a*b)@Wa^T partial -> atomic A
// 128 rows x 256 out-cols (128 a-cols + same 128 b-cols), 4 waves of 32x256.
__global__ __launch_bounds__(256) void k2_gemm2(const unsigned short* __restrict__ hB,
                                                const unsigned short* __restrict__ W2B,
                                                const float* __restrict__ bv,
                                                const float* __restrict__ bu,
                                                const float* __restrict__ Wa,
                                                float* __restrict__ Aws) {
  __shared__ __align__(16) unsigned short hs[128 * 64];   // 16KB
  __shared__ __align__(16) unsigned short wt[256 * 64];   // 32KB
  const int tid = threadIdx.x, lane = tid & 63, wv = tid >> 6;
  const int cbk = blockIdx.x & 1, rbk = blockIdx.x >> 1;
  const int row0 = rbk << 7;
  const int q = lane >> 4, c15 = lane & 15;

  f32x4 acc[2][16];
#pragma unroll
  for (int i = 0; i < 2; ++i)
#pragma unroll
    for (int j = 0; j < 16; ++j) acc[i][j] = {0.f, 0.f, 0.f, 0.f};

  for (int kk = 0; kk < L; kk += 64) {
    __syncthreads();
#pragma unroll
    for (int i = 0; i < 4; ++i) {
      const int g = (wv << 2) + i;
      const int slot = (g << 6) + lane;
      const int j = slot >> 3;
      const int s = slot & 7;
      const int k8 = s ^ (j & 7);
      GLDS16(hB + (size_t)(row0 + j) * L + kk + (k8 << 3), hs + (g << 9));
    }
#pragma unroll
    for (int i = 0; i < 8; ++i) {
      const int g = (wv << 3) + i;
      const int slot = (g << 6) + lane;
      const int j = slot >> 3;
      const int s = slot & 7;
      const int k8 = s ^ (j & 7);
      const int w2row = (j < 128) ? ((cbk << 7) + j) : (DD + (cbk << 7) + (j - 128));
      GLDS16(W2B + (size_t)w2row * L + kk + (k8 << 3), wt + (g << 9));
    }
    __syncthreads();
#pragma unroll
    for (int ks = 0; ks < 2; ++ks) {
      const int ch = (ks << 2) + q;
      bf16x8 af[2];
#pragma unroll
      for (int mt = 0; mt < 2; ++mt) {
        const int rr = (wv << 5) + (mt << 4) + c15;
        af[mt] = *(const bf16x8*)(hs + (rr << 6) + ((ch ^ (rr & 7)) << 3));
      }
#pragma unroll
      for (int nt = 0; nt < 16; ++nt) {
        const int jj = (nt << 4) + c15;
        const bf16x8 bb = *(const bf16x8*)(wt + (jj << 6) + ((ch ^ (jj & 7)) << 3));
        acc[0][nt] = __builtin_amdgcn_mfma_f32_16x16x32_bf16(af[0], bb, acc[0][nt], 0, 0, 0);
        acc[1][nt] = __builtin_amdgcn_mfma_f32_16x16x32_bf16(af[1], bb, acc[1][nt], 0, 0, 0);
      }
    }
  }
  // epilogue
  float wa0[8], wa1[8], bvv[8], buv[8];
#pragma unroll
  for (int nt = 0; nt < 8; ++nt) {
    const int d = (cbk << 7) + (nt << 4) + c15;
    wa0[nt] = Wa[d]; wa1[nt] = Wa[DD + d];
    bvv[nt] = bv[d]; buv[nt] = bu[d];
  }
#pragma unroll
  for (int mt = 0; mt < 2; ++mt) {
#pragma unroll
    for (int r = 0; r < 4; ++r) {
      const int rowg = row0 + (wv << 5) + (mt << 4) + (q << 2) + r;
      float p0 = 0.f, p1 = 0.f;
#pragma unroll
      for (int nt = 0; nt < 8; ++nt) {
        const float av = ftanh(acc[mt][nt][r] + bvv[nt]);
        const float bx = fsig(acc[mt][nt + 8][r] + buv[nt]);
        const float ab = av * bx;
        p0 += ab * wa0[nt];
        p1 += ab * wa1[nt];
      }
#pragma unroll
      for (int off = 1; off < 16; off <<= 1) {
        p0 += __shfl_xor(p0, off, 64);
        p1 += __shfl_xor(p1, off, 64);
      }
      if (c15 == 0) {
        atomicAdd(&Aws[(rowg << 1)], p0);
        atomicAdd(&Aws[(rowg << 1) + 1], p1);
      }
    }
  }
}

// ------ K3a: elementwise: A=Aws+ba -> out, exp-sums z/s, key min/max
__global__ void k3a_elem(const float* __restrict__ Aws, const float* __restrict__ tws,
                         const float* __restrict__ ba, const int* __restrict__ lblp,
                         float* __restrict__ out,
                         float* __restrict__ scalF, unsigned* __restrict__ scalU) {
  const int row = blockIdx.x * 256 + threadIdx.x;
  const int lane = threadIdx.x & 63;
  const float2 Ap = ((const float2*)Aws)[row];
  const float2 tp = ((const float2*)tws)[row];
  const float A0 = Ap.x + ba[0];
  const float A1 = Ap.y + ba[1];
  out[4 + row] = A0;
  out[4 + NROWS + row] = A1;
  const float e0 = __expf(A0), e1 = __expf(A1);
  float z0 = e0, z1 = e1, s0 = e0 * tp.x, s1 = e1 * tp.y;
  const int lbl = *lblp;
  unsigned u = encf(lbl ? A1 : A0);
  unsigned umin = u, umax = u;
#pragma unroll
  for (int off = 1; off < 64; off <<= 1) {
    z0 += __shfl_xor(z0, off, 64);
    z1 += __shfl_xor(z1, off, 64);
    s0 += __shfl_xor(s0, off, 64);
    s1 += __shfl_xor(s1, off, 64);
    const unsigned om = (unsigned)__shfl_xor((int)umin, off, 64);
    const unsigned oM = (unsigned)__shfl_xor((int)umax, off, 64);
    umin = umin < om ? umin : om;
    umax = umax > oM ? umax : oM;
  }
  if (lane == 0) {
    atomicAdd(&scalF[0], z0); atomicAdd(&scalF[1], z1);
    atomicAdd(&scalF[2], s0); atomicAdd(&scalF[3], s1);
    atomicMin(&scalU[0], umin);
    atomicMax(&scalU[1], umax);
  }
}

// ------ K3b: linear-bin histogram with per-block LDS pre-aggregation
__global__ __launch_bounds__(1024) void k3b_hist(const float* __restrict__ out,
                                                 const int* __restrict__ lblp,
                                                 const unsigned* __restrict__ scalU,
                                                 unsigned* __restrict__ hist) {
  __shared__ unsigned lh[NBINS];
  const int tid = threadIdx.x;
  for (int i = tid; i < NBINS; i += 1024) lh[i] = 0u;
  __syncthreads();
  const int lbl = *lblp;
  const int row = blockIdx.x * 1024 + tid;
  const float A = out[4 + (size_t)lbl * NROWS + row];
  const float mn = decf(scalU[0]);
  const float mx = decf(scalU[1]);
  const float scale = (mx > mn) ? (float)(NBINS - 1) / (mx - mn) : 0.f;
  int bin = (int)((A - mn) * scale);
  bin = bin < 0 ? 0 : (bin > NBINS - 1 ? NBINS - 1 : bin);
  atomicAdd(&lh[bin], 1u);
  __syncthreads();
  for (int i = tid; i < NBINS; i += 1024) {
    const unsigned c = lh[i];
    if (c) atomicAdd(&hist[i], c);
  }
}

// -------- K4: hist scan -> threshold bins; bag logits + y_proba -> out[0..3]
__global__ void k4_scan(const unsigned* __restrict__ hist,
                        const float* __restrict__ scalF,
                        unsigned* __restrict__ scalU,
                        const float* __restrict__ bbag,
                        float* __restrict__ out) {
  __shared__ unsigned csum[256];
  const int t = threadIdx.x;
  unsigned s = 0;
  for (int b = 0; b < 64; ++b) s += hist[t * 64 + b];
  csum[t] = s;
  __syncthreads();
  if (t == 0) {
    unsigned acc = 0; int ch = 255;
    for (; ch > 0; --ch) { if (acc + csum[ch] >= NI) break; acc += csum[ch]; }
    unsigned binHi = 0;
    for (int b = ch * 64 + 63; b >= ch * 64; --b) { acc += hist[b]; if (acc >= NI) { binHi = (unsigned)b; break; } }
    scalU[6] = binHi;
    acc = 0; int cl = 0;
    for (; cl < 255; ++cl) { if (acc + csum[cl] >= NI) break; acc += csum[cl]; }
    unsigned binLo = NBINS - 1;
    for (int b = cl * 64; b < cl * 64 + 64; ++b) { acc += hist[b]; if (acc >= NI) { binLo = (unsigned)b; break; } }
    scalU[7] = binLo;
    const float l0 = scalF[2] / scalF[0] + bbag[0];
    const float l1 = scalF[3] / scalF[1] + bbag[1];
    const float m = fmaxf(l0, l1);
    const float e0 = __expf(l0 - m), e1 = __expf(l1 - m);
    const float inv = 1.0f / (e0 + e1);
    out[0] = l0; out[1] = l1; out[2] = e0 * inv; out[3] = e1 * inv;
  }
}

// ----------------------------- K5: collect top/bottom candidates by bin
__global__ void k5_collect(const float* __restrict__ out,
                           const int* __restrict__ lblp,
                           unsigned* __restrict__ scalU,
                           unsigned* __restrict__ chK, unsigned* __restrict__ chI,
                           unsigned* __restrict__ clK, unsigned* __restrict__ clI) {
  const int binHi = (int)scalU[6], binLo = (int)scalU[7];
  const float mn = decf(scalU[0]);
  const float mx = decf(scalU[1]);
  const float scale = (mx > mn) ? (float)(NBINS - 1) / (mx - mn) : 0.f;
  const int lbl = *lblp;
  const float* Ap = out + 4 + (size_t)lbl * NROWS;
  const int n = blockIdx.x * 256 + threadIdx.x;
  const float A = Ap[n];
  int bin = (int)((A - mn) * scale);
  bin = bin < 0 ? 0 : (bin > NBINS - 1 ? NBINS - 1 : bin);
  const unsigned u = encf(A);
  if (bin >= binHi) { unsigned p = atomicAdd(&scalU[4], 1u); if (p < CAP) { chK[p] = u; chI[p] = (unsigned)n; } }
  if (bin <= binLo) { unsigned p = atomicAdd(&scalU[5], 1u); if (p < CAP) { clK[p] = u; clI[p] = (unsigned)n; } }
}

// -------- K6: exact rank selection + instance logits + SmoothTop1SVM loss
__global__ __launch_bounds__(256) void k6_loss(const unsigned* __restrict__ scalU,
                                               const unsigned* __restrict__ chK, const unsigned* __restrict__ chI,
                                               const unsigned* __restrict__ clK, const unsigned* __restrict__ clI,
                                               const unsigned short* __restrict__ hB,
                                               const float* __restrict__ Winst,
                                               const float* __restrict__ binst,
                                               const int* __restrict__ lblp,
                                               float* __restrict__ out) {
  __shared__ unsigned kH[CAP], iH[CAP], kL[CAP], iL[CAP];
  __shared__ int selT[NI], selB[NI];
  __shared__ float lossA[256];
  const int t = threadIdx.x;
  const int lbl = *lblp;
  const unsigned cH = scalU[4], cL = scalU[5];
  const int nH = (int)(cH < CAP ? cH : CAP);
  const int nL = (int)(cL < CAP ? cL : CAP);
  if (t < NI) { selT[t] = 0; selB[t] = 0; }
  for (int i = t; i < nH; i += 256) { kH[i] = chK[i]; iH[i] = chI[i]; }
  for (int i = t; i < nL; i += 256) { kL[i] = clK[i]; iL[i] = clI[i]; }
  __syncthreads();
  for (int c = t; c < nH; c += 256) {
    const unsigned k = kH[c], id = iH[c];
    int rank = 0;
    for (int j = 0; j < nH; ++j) rank += (kH[j] > k) || (kH[j] == k && iH[j] < id);
    if (rank < NI) selT[rank] = (int)id;
  }
  for (int c = t; c < nL; c += 256) {
    const unsigned k = kL[c], id = iL[c];
    int rank = 0;
    for (int j = 0; j < nL; ++j) rank += (kL[j] < k) || (kL[j] == k && iL[j] < id);
    if (rank < NI) selB[rank] = (int)id;
  }
  __syncthreads();
  float loss = 0.f;
  if (t < 2 * NI) {
    const int idx = (t < NI) ? selT[t] : selB[t - NI];
    const int target = (t < NI) ? 1 : 0;
    const unsigned short* hp = hB + (size_t)idx * L;
    const float* w0 = Winst + (size_t)lbl * 2 * L;
    const float* w1 = w0 + L;
    float l0 = binst[lbl * 2 + 0], l1 = binst[lbl * 2 + 1];
    for (int k = 0; k < L; ++k) {
      const float hv = bf2f(hp[k]);
      l0 += hv * w0[k];
      l1 += hv * w1[k];
    }
    const float z0 = l0 + (target ? 1.0f : 0.0f);
    const float z1 = l1 + (target ? 0.0f : 1.0f);
    const float m = fmaxf(z0, z1);
    const float lse = m + logf(__expf(z0 - m) + __expf(z1 - m));
    loss = lse - (target ? l1 : l0);
  }
  lossA[t] = loss;
  __syncthreads();
  for (int sft = 128; sft; sft >>= 1) {
    if (t < sft) lossA[t] += lossA[t + sft];
    __syncthreads();
  }
  if (t == 0) out[4 + 2 * NROWS] = lossA[0] / 100.0f;
}

extern "C" void kernel_launch(void* const* d_in, const int* in_sizes, int n_in,
                              void* d_out, int out_size, void* d_ws, size_t ws_size,
                              hipStream_t stream) {
  const float* x     = (const float*)d_in[0];
  const int*   lbl   = (const int*)d_in[1];
  const float* Wc    = (const float*)d_in[2];
  const float* bc    = (const float*)d_in[3];
  const float* Wv    = (const float*)d_in[4];
  const float* bv    = (const float*)d_in[5];
  const float* Wu    = (const float*)d_in[6];
  const float* bu    = (const float*)d_in[7];
  const float* Wa    = (const float*)d_in[8];
  const float* ba    = (const float*)d_in[9];
  const float* Winst = (const float*)d_in[10];
  const float* binst = (const float*)d_in[11];
  const float* Wbag  = (const float*)d_in[12];
  const float* bbag  = (const float*)d_in[13];
  float* out = (float*)d_out;
  char* ws = (char*)d_ws;

  unsigned short* hB   = (unsigned short*)(ws);                  // 134217728 B
  unsigned short* WcB  = (unsigned short*)(ws + 134217728LL);    // 1048576 B
  unsigned short* W2B  = (unsigned short*)(ws + 135266304LL);    // 524288 B
  float*          Aws  = (float*)(ws + 135790592LL);             // 1048576 B
  float*          tws  = (float*)(ws + 136839168LL);             // 1048576 B
  unsigned*       hist = (unsigned*)(ws + 137887744LL);          // 65536 B
  float*          scalF= (float*)(ws + 137953280LL);             // 64 B
  unsigned*       scalU= (unsigned*)(ws + 137953344LL);          // 64 B
  unsigned*       chK  = (unsigned*)(ws + 137953408LL);          // 4*CAP*4 B
  unsigned*       chI  = chK + CAP;
  unsigned*       clK  = chI + CAP;
  unsigned*       clI  = clK + CAP;

  k0_init<<<2048, 256, 0, stream>>>(Wc, Wv, Wu, WcB, W2B, Aws, tws, hist, scalF, scalU);
  k1_gemm1<<<2048, 256, 0, stream>>>(x, WcB, bc, Wbag, hB, tws);
  k2_gemm2<<<2048, 256, 0, stream>>>(hB, W2B, bv, bu, Wa, Aws);
  k3a_elem<<<512, 256, 0, stream>>>(Aws, tws, ba, lbl, out, scalF, scalU);
  k3b_hist<<<128, 1024, 0, stream>>>(out, lbl, scalU, hist);
  k4_scan<<<1, 256, 0, stream>>>(hist, scalF, scalU, bbag, out);
  k5_collect<<<512, 256, 0, stream>>>(out, lbl, scalU, chK, chI, clK, clI);
  k6_loss<<<1, 256, 0, stream>>>(scalU, chK, chI, clK, clI, hB, Winst, binst, lbl, out);
}